// Round 1
// baseline (175.799 us; speedup 1.0000x reference)
//
#include <hip/hip_runtime.h>

#define HH 512
#define WW 512
#define NB 32
#define EPSF 1e-7f
#define DTF 0.05f
#define RS1 4      // rows per wave, pass 1 (128 strips/image -> 4096 waves)
#define RSF 8      // output rows per wave, pass 2
#define PANW 256   // panel width, pass 2 (4 cols/lane -> halved register state)

// lane-to-lane pull via LDS-pipe permute (no LDS storage)
__device__ __forceinline__ float bperm(int addr, float v) {
    return __int_as_float(__builtin_amdgcn_ds_bpermute(addr, __float_as_int(v)));
}

// ---------------- Pass 1: partial max of e4, 8 cols/lane, full-width rows ----------------
struct R10 { float v[10]; };

__device__ __forceinline__ void load_row10(const float* __restrict__ base, int row,
                                           int lane, int bpu, int bpd,
                                           bool lo, bool hi, R10& r) {
    if ((unsigned)row < (unsigned)HH) {               // wave-uniform branch
        const float4* p = (const float4*)(base + row * WW + 8 * lane);
        float4 a = p[0], b = p[1];
        r.v[1] = a.x; r.v[2] = a.y; r.v[3] = a.z; r.v[4] = a.w;
        r.v[5] = b.x; r.v[6] = b.y; r.v[7] = b.z; r.v[8] = b.w;
    } else {
        #pragma unroll
        for (int k = 1; k <= 8; ++k) r.v[k] = 0.f;
    }
    float l = bperm(bpu, r.v[8]);   // lane-1's col 8l-1
    float h = bperm(bpd, r.v[1]);   // lane+1's col 8l+8
    r.v[0] = lo ? 0.f : l;
    r.v[9] = hi ? 0.f : h;
}

__global__ __launch_bounds__(256, 4)
void max_e4_kernel(const float* __restrict__ img, float* __restrict__ partial) {
    const int wid  = blockIdx.x * 4 + (threadIdx.x >> 6);
    const int lane = threadIdx.x & 63;
    const int rs = wid & 127;                // 128 strips of RS1 rows
    const int b  = wid >> 7;
    const int i0 = rs * RS1;
    const float* __restrict__ IM = img + (size_t)b * (HH * WW);
    const bool lo = (lane == 0), hi = (lane == 63);
    const int bpu = ((lane + 63) & 63) << 2, bpd = ((lane + 1) & 63) << 2;

    R10 A, B, C;
    load_row10(IM, i0 - 1, lane, bpu, bpd, lo, hi, A);
    load_row10(IM, i0,     lane, bpu, bpd, lo, hi, B);
    float m = 0.f;
    #pragma unroll
    for (int i = i0; i < i0 + RS1; ++i) {
        load_row10(IM, i + 1, lane, bpu, bpd, lo, hi, C);
        #pragma unroll
        for (int k = 1; k <= 8; ++k) {
            float ex = (A.v[k-1] - A.v[k+1]) + 2.f * (B.v[k-1] - B.v[k+1]) + (C.v[k-1] - C.v[k+1]);
            float ey = (A.v[k-1] - C.v[k-1]) + 2.f * (A.v[k] - C.v[k]) + (A.v[k+1] - C.v[k+1]);
            float s2 = ex * ex + ey * ey;
            m = fmaxf(m, s2 * s2);
        }
        A = B; B = C;
    }
    for (int off = 32; off > 0; off >>= 1)
        m = fmaxf(m, __shfl_down(m, off, 64));
    if (lane == 0) partial[wid] = m;         // 4096 partials, all written
}

// ---------------- Pass 2: wave-per-half-row-panel fused forcing function ----------------
// 4 cols/lane: v[1..4] = cols c0+4l .. c0+4l+3 ; v[0]/v[5] halo cols ; x = outer
// halo col (c0-2 on lane 0 / c0+PANW+1 on lane 63) used to compute e/px at the
// panel-boundary column locally (neighbor panel lives in another wave).
struct R7 { float v[6]; float x; };

__device__ __forceinline__ void load_row(const float* __restrict__ base, int row,
                                         int lane, int c0, int bpu, int bpd,
                                         bool actL, bool actR, bool zL, bool zR, R7& r) {
    if ((unsigned)row < (unsigned)HH) {               // wave-uniform branch
        const float* rp = base + (size_t)row * WW;
        const float4 a = *(const float4*)(rp + c0 + 4 * lane);
        r.v[1] = a.x; r.v[2] = a.y; r.v[3] = a.z; r.v[4] = a.w;
        float l = bperm(bpu, r.v[4]);
        float h = bperm(bpd, r.v[1]);
        float xx = 0.f;
        if (actL | actR) {                            // exactly one lane active per wave
            const float2 t = *(const float2*)(rp + (actL ? c0 - 2 : c0 + PANW));
            if (actL) { l = t.y; xx = t.x; }          // cols c0-2, c0-1
            else      { h = t.x; xx = t.y; }          // cols c0+PANW, c0+PANW+1
        }
        r.v[0] = zL ? 0.f : l;
        r.v[5] = zR ? 0.f : h;
        r.x = xx;
    } else {
        #pragma unroll
        for (int k = 0; k < 6; ++k) r.v[k] = 0.f;
        r.x = 0.f;
    }
}

__global__ __launch_bounds__(256, 4)
void fused_ff(const float* __restrict__ u, const float* __restrict__ img,
              const float* __restrict__ pa, const float* __restrict__ pb,
              const float* __restrict__ pg, const float* __restrict__ partial,
              float* __restrict__ out) {
    // folded reduce_max: every block redundantly reduces the 4096 L2-hot partials
    __shared__ float sred[4];
    {
        float v = 0.f;
        #pragma unroll
        for (int k = 0; k < 16; ++k)
            v = fmaxf(v, partial[threadIdx.x + 256 * k]);
        for (int off = 32; off > 0; off >>= 1)
            v = fmaxf(v, __shfl_down(v, off, 64));
        if ((threadIdx.x & 63) == 0) sred[threadIdx.x >> 6] = v;
    }
    __syncthreads();
    const float M = fmaxf(fmaxf(sred[0], sred[1]), fmaxf(sred[2], sred[3]));

    const int wid  = blockIdx.x * 4 + (threadIdx.x >> 6);
    const int lane = threadIdx.x & 63;
    const int p  = wid & 1;                  // panel
    const int rs = (wid >> 1) & 63;          // 64 strips of RSF rows
    const int b  = wid >> 7;
    const int o0 = rs * RSF;
    const int c0 = p * PANW;
    const size_t base = (size_t)b * (HH * WW);
    const float* __restrict__ U  = u + base;
    const float* __restrict__ IM = img + base;
    float* __restrict__ O = out + base;
    const int bpu = ((lane + 63) & 63) << 2, bpd = ((lane + 1) & 63) << 2;
    const bool l0 = (lane == 0), l63 = (lane == 63);
    const bool actL = l0  && (c0 > 0);           // panel-interior left edge
    const bool actR = l63 && (c0 + PANW < WW);   // panel-interior right edge
    const bool zL = l0 && !actL, zR = l63 && !actR;  // true image borders

    const float dta = DTF * pa[0];
    const float dtb = 20.f * DTF * pb[0];
    const float dtg = DTF * pg[0];

    // rolling state (all registers): img rows o,o+1 ; u rows o-1..o+1 ; e/px/py history
    R7 I0 = {}, I1 = {}, R1 = {}, R2 = {};
    float E2[6] = {}, PX2[6] = {};
    float R0[5] = {}, E1[5] = {}, PY1[5] = {}, PY2[5] = {};

    if (o0 >= 2) {   // wave-uniform preload of rows o0-2, o0-1
        load_row(IM, o0 - 2, lane, c0, bpu, bpd, actL, actR, zL, zR, I0);
        load_row(IM, o0 - 1, lane, c0, bpu, bpd, actL, actR, zL, zR, I1);
        load_row(U,  o0 - 2, lane, c0, bpu, bpd, actL, actR, zL, zR, R1);
        load_row(U,  o0 - 1, lane, c0, bpu, bpd, actL, actR, zL, zR, R2);
    }

    #pragma unroll
    for (int o = o0 - 2; o < o0 + RSF; ++o) {
        R7 C, W;
        load_row(IM, o + 2, lane, c0, bpu, bpd, actL, actR, zL, zR, C);
        load_row(U,  o + 2, lane, c0, bpu, bpd, actL, actR, zL, zR, W);

        // e / px / py at row o+1 (img rows o,o+1,o+2 ; u rows o..o+2)
        float eN[6], PXN[6], PYN[5];
        const bool rowv = (o >= -1) && (o < HH - 1);   // wave-uniform row validity
        if (rowv) {
            #pragma unroll
            for (int k = 1; k <= 4; ++k) {
                float ex = (I0.v[k-1] - I0.v[k+1]) + 2.f * (I1.v[k-1] - I1.v[k+1]) + (C.v[k-1] - C.v[k+1]);
                float ey = (I0.v[k-1] - C.v[k-1]) + 2.f * (I0.v[k] - C.v[k]) + (I0.v[k+1] - C.v[k+1]);
                float s2 = ex * ex + ey * ey;
                eN[k] = M * __builtin_amdgcn_rcpf(s2 * s2 + M);
                float gux = R2.v[k+1] - R2.v[k-1];
                float guy = R1.v[k] - W.v[k];
                float rn  = __builtin_amdgcn_rsqf(gux * gux + guy * guy + EPSF);
                PXN[k] = gux * rn;
                PYN[k] = guy * rn;
            }
        } else {
            #pragma unroll
            for (int k = 1; k <= 4; ++k) { eN[k] = 0.f; PXN[k] = 0.f; PYN[k] = 0.f; }
        }
        {   // halos for eN / PXN: interior lanes via bperm, image borders zero
            float a = bperm(bpu, eN[4]),  bb = bperm(bpd, eN[1]);
            float c = bperm(bpu, PXN[4]), d  = bperm(bpd, PXN[1]);
            eN[0]  = zL ? 0.f : a;  eN[5]  = zR ? 0.f : bb;
            PXN[0] = zL ? 0.f : c;  PXN[5] = zR ? 0.f : d;
        }
        if (rowv && (actL | actR)) {
            // panel-boundary halo column: recompute e/px locally on the edge lane
            float i0a = actL ? I0.x    : I0.v[4];
            float i0b = actL ? I0.v[0] : I0.v[5];
            float i0c = actL ? I0.v[1] : I0.x;
            float i1a = actL ? I1.x    : I1.v[4];
            float i1c = actL ? I1.v[1] : I1.x;
            float ca  = actL ? C.x     : C.v[4];
            float cb  = actL ? C.v[0]  : C.v[5];
            float cc  = actL ? C.v[1]  : C.x;
            float ex = (i0a - i0c) + 2.f * (i1a - i1c) + (ca - cc);
            float ey = (i0a - ca) + 2.f * (i0b - cb) + (i0c - cc);
            float s2 = ex * ex + ey * ey;
            float eh = M * __builtin_amdgcn_rcpf(s2 * s2 + M);
            float gux = actL ? (R2.v[1] - R2.x)    : (R2.x - R2.v[4]);
            float guy = actL ? (R1.v[0] - W.v[0])  : (R1.v[5] - W.v[5]);
            float rn = __builtin_amdgcn_rsqf(gux * gux + guy * guy + EPSF);
            float ph = gux * rn;
            if (actL) { eN[0] = eh; PXN[0] = ph; }
            else      { eN[5] = eh; PXN[5] = ph; }
        }

        if (o >= o0) {   // emit output row o
            float vals[4];
            #pragma unroll
            for (int k = 1; k <= 4; ++k) {
                float gex = E2[k+1] - E2[k-1];
                float gey = E1[k] - eN[k];
                float xp = R1.v[k+1] - R1.v[k], xn = R1.v[k] - R1.v[k-1];
                float yp = R0[k] - R1.v[k],     yn = R1.v[k] - R2.v[k];
                float tr = fmaxf(gex, 0.f) * xp + fminf(gex, 0.f) * xn
                         + fmaxf(gey, 0.f) * yp + fminf(gey, 0.f) * yn;
                float gxc = R1.v[k+1] - R1.v[k-1], gyc = R0[k] - R2.v[k];
                float ncv = __builtin_amdgcn_sqrtf(gxc * gxc + gyc * gyc + EPSF);
                float kap = (PX2[k+1] - PX2[k-1]) + (PY1[k] - PYN[k]);
                vals[k-1] = R1.v[k] + E2[k] * ncv * (kap * dta + dtg) + tr * dtb;
            }
            *(float4*)(O + (size_t)o * WW + c0 + 4 * lane) =
                make_float4(vals[0], vals[1], vals[2], vals[3]);
        }

        // roll
        I0 = I1; I1 = C;
        #pragma unroll
        for (int k = 1; k <= 4; ++k) { R0[k] = R1.v[k]; E1[k] = E2[k]; PY1[k] = PY2[k]; PY2[k] = PYN[k]; }
        R1 = R2; R2 = W;
        #pragma unroll
        for (int k = 0; k < 6; ++k) { E2[k] = eN[k]; PX2[k] = PXN[k]; }
    }
}

extern "C" void kernel_launch(void* const* d_in, const int* in_sizes, int n_in,
                              void* d_out, int out_size, void* d_ws, size_t ws_size,
                              hipStream_t stream) {
    const float* u   = (const float*)d_in[0];
    const float* img = (const float*)d_in[1];
    const float* pa  = (const float*)d_in[2];
    const float* pb  = (const float*)d_in[3];
    const float* pg  = (const float*)d_in[4];
    float* out = (float*)d_out;
    float* partial = (float*)d_ws;        // 4096 floats, all written unconditionally

    // pass 1: 128 strips x 32 batch = 4096 waves = 1024 blocks (4 blocks/CU)
    max_e4_kernel<<<1024, 256, 0, stream>>>(img, partial);
    // pass 2: 2 panels x 64 strips x 32 batch = 4096 waves = 1024 blocks (4 blocks/CU)
    fused_ff<<<1024, 256, 0, stream>>>(u, img, pa, pb, pg, partial, out);
}

// Round 3
// 127.893 us; speedup vs baseline: 1.3746x; 1.3746x over previous
//
#include <hip/hip_runtime.h>

#define HH 512
#define WW 512
#define NB 32
#define EPSF 1e-7f
#define DTF 0.05f
#define RS1 4      // rows per wave, pass 1 (128 strips/image -> 4096 waves)
#define RSF 8      // output rows per wave, pass 2
#define PANW 256   // panel width, pass 2 (4 cols/lane -> halved register state)

// lane-to-lane pull via LDS-pipe permute (no LDS storage)
__device__ __forceinline__ float bperm(int addr, float v) {
    return __int_as_float(__builtin_amdgcn_ds_bpermute(addr, __float_as_int(v)));
}

// ---------------- Pass 1: partial max of e4, 8 cols/lane, full-width rows ----------------
struct R10 { float v[10]; };

__device__ __forceinline__ void load_row10(const float* __restrict__ base, int row,
                                           int lane, int bpu, int bpd,
                                           bool lo, bool hi, R10& r) {
    if ((unsigned)row < (unsigned)HH) {               // wave-uniform branch
        const float4* p = (const float4*)(base + row * WW + 8 * lane);
        float4 a = p[0], b = p[1];
        r.v[1] = a.x; r.v[2] = a.y; r.v[3] = a.z; r.v[4] = a.w;
        r.v[5] = b.x; r.v[6] = b.y; r.v[7] = b.z; r.v[8] = b.w;
    } else {
        #pragma unroll
        for (int k = 1; k <= 8; ++k) r.v[k] = 0.f;
    }
    float l = bperm(bpu, r.v[8]);   // lane-1's col 8l-1
    float h = bperm(bpd, r.v[1]);   // lane+1's col 8l+8
    r.v[0] = lo ? 0.f : l;
    r.v[9] = hi ? 0.f : h;
}

__global__ __launch_bounds__(256, 4)
void max_e4_kernel(const float* __restrict__ img, float* __restrict__ partial) {
    const int wid  = blockIdx.x * 4 + (threadIdx.x >> 6);
    const int lane = threadIdx.x & 63;
    const int rs = wid & 127;                // 128 strips of RS1 rows
    const int b  = wid >> 7;
    const int i0 = rs * RS1;
    const float* __restrict__ IM = img + (size_t)b * (HH * WW);
    const bool lo = (lane == 0), hi = (lane == 63);
    const int bpu = ((lane + 63) & 63) << 2, bpd = ((lane + 1) & 63) << 2;

    R10 A, B, C;
    load_row10(IM, i0 - 1, lane, bpu, bpd, lo, hi, A);
    load_row10(IM, i0,     lane, bpu, bpd, lo, hi, B);
    float m = 0.f;
    #pragma unroll
    for (int i = i0; i < i0 + RS1; ++i) {
        load_row10(IM, i + 1, lane, bpu, bpd, lo, hi, C);
        #pragma unroll
        for (int k = 1; k <= 8; ++k) {
            float ex = (A.v[k-1] - A.v[k+1]) + 2.f * (B.v[k-1] - B.v[k+1]) + (C.v[k-1] - C.v[k+1]);
            float ey = (A.v[k-1] - C.v[k-1]) + 2.f * (A.v[k] - C.v[k]) + (A.v[k+1] - C.v[k+1]);
            float s2 = ex * ex + ey * ey;
            m = fmaxf(m, s2 * s2);
        }
        A = B; B = C;
    }
    for (int off = 32; off > 0; off >>= 1)
        m = fmaxf(m, __shfl_down(m, off, 64));
    if (lane == 0) partial[wid] = m;         // 4096 partials, all written
}

// ---------------- Pass 2: wave-per-half-row-panel fused forcing function ----------------
// 4 cols/lane: v[1..4] = cols c0+4l .. c0+4l+3 ; v[0]/v[5] halo cols ; x = outer
// halo col (c0-2 on lane 0 / c0+PANW+1 on lane 63) used to compute e/px at the
// panel-boundary column locally (neighbor panel lives in another wave).
struct R7 { float v[6]; float x; };
struct RawR { float4 a; float2 t; };

// phase 1: issue the global loads only (no lgkm wait yet)
__device__ __forceinline__ void load_raw(const float* __restrict__ base, int row,
                                         int lane, int c0, bool actL, bool actR, RawR& r) {
    if ((unsigned)row < (unsigned)HH) {               // wave-uniform branch
        const float* rp = base + (size_t)row * WW;
        r.a = *(const float4*)(rp + c0 + 4 * lane);
        if (actL | actR)                              // exactly one lane active per wave
            r.t = *(const float2*)(rp + (actL ? c0 - 2 : c0 + PANW));
        else
            r.t = make_float2(0.f, 0.f);
    } else {
        r.a = make_float4(0.f, 0.f, 0.f, 0.f);
        r.t = make_float2(0.f, 0.f);
    }
}

// phase 2: halo exchange via bperm (zeroed raw rows give zeros -> still correct)
__device__ __forceinline__ void finish_row(const RawR& q, int bpu, int bpd,
                                           bool actL, bool actR, bool zL, bool zR, R7& r) {
    r.v[1] = q.a.x; r.v[2] = q.a.y; r.v[3] = q.a.z; r.v[4] = q.a.w;
    float l = bperm(bpu, r.v[4]);
    float h = bperm(bpd, r.v[1]);
    float xx = 0.f;
    if (actL) { l = q.t.y; xx = q.t.x; }              // cols c0-2, c0-1
    if (actR) { h = q.t.x; xx = q.t.y; }              // cols c0+PANW, c0+PANW+1
    r.v[0] = zL ? 0.f : l;
    r.v[5] = zR ? 0.f : h;
    r.x = xx;
}

__device__ __forceinline__ void load_row(const float* __restrict__ base, int row,
                                         int lane, int c0, int bpu, int bpd,
                                         bool actL, bool actR, bool zL, bool zR, R7& r) {
    RawR q;
    load_raw(base, row, lane, c0, actL, actR, q);
    finish_row(q, bpu, bpd, actL, actR, zL, zR, r);
}

// (256,3): VGPR cap ~170. (256,4) capped at 128 -> allocator spilled the rolling
// stencil state to scratch (round 1: VGPR=64, WRITE_SIZE 94MB vs 33MB ideal, 81us).
__global__ __launch_bounds__(256, 3)
void fused_ff(const float* __restrict__ u, const float* __restrict__ img,
              const float* __restrict__ pa, const float* __restrict__ pb,
              const float* __restrict__ pg, const float* __restrict__ partial,
              float* __restrict__ out) {
    // scalar params: issue these loads before the reduction so they're free
    const float va = pa[0], vb = pb[0], vg = pg[0];

    // folded reduce_max: every block redundantly reduces the 4096 L2-hot partials
    __shared__ float sred[4];
    {
        float v = 0.f;
        #pragma unroll
        for (int k = 0; k < 16; ++k)
            v = fmaxf(v, partial[threadIdx.x + 256 * k]);
        for (int off = 32; off > 0; off >>= 1)
            v = fmaxf(v, __shfl_down(v, off, 64));
        if ((threadIdx.x & 63) == 0) sred[threadIdx.x >> 6] = v;
    }
    __syncthreads();
    const float M = fmaxf(fmaxf(sred[0], sred[1]), fmaxf(sred[2], sred[3]));

    const int wid  = blockIdx.x * 4 + (threadIdx.x >> 6);
    const int lane = threadIdx.x & 63;
    const int p  = wid & 1;                  // panel
    const int rs = (wid >> 1) & 63;          // 64 strips of RSF rows
    const int b  = wid >> 7;
    const int o0 = rs * RSF;
    const int c0 = p * PANW;
    const size_t base = (size_t)b * (HH * WW);
    const float* __restrict__ U  = u + base;
    const float* __restrict__ IM = img + base;
    float* __restrict__ O = out + base;
    const int bpu = ((lane + 63) & 63) << 2, bpd = ((lane + 1) & 63) << 2;
    const bool l0 = (lane == 0), l63 = (lane == 63);
    const bool actL = l0  && (c0 > 0);           // panel-interior left edge
    const bool actR = l63 && (c0 + PANW < WW);   // panel-interior right edge
    const bool zL = l0 && !actL, zR = l63 && !actR;  // true image borders

    const float dta = DTF * va;
    const float dtb = 20.f * DTF * vb;
    const float dtg = DTF * vg;

    // rolling state (all registers): img rows o,o+1 ; u rows o-1..o+1 ; e/px/py history
    R7 I0 = {}, I1 = {}, R1 = {}, R2 = {};
    float E2[6] = {}, PX2[6] = {};
    float R0[5] = {}, E1[5] = {}, PY1[5] = {}, PY2[5] = {};

    if (o0 >= 2) {   // wave-uniform preload of rows o0-2, o0-1
        load_row(IM, o0 - 2, lane, c0, bpu, bpd, actL, actR, zL, zR, I0);
        load_row(IM, o0 - 1, lane, c0, bpu, bpd, actL, actR, zL, zR, I1);
        load_row(U,  o0 - 2, lane, c0, bpu, bpd, actL, actR, zL, zR, R1);
        load_row(U,  o0 - 1, lane, c0, bpu, bpd, actL, actR, zL, zR, R2);
    }

    #pragma unroll
    for (int o = o0 - 2; o < o0 + RSF; ++o) {
        // issue BOTH row loads before any bperm forces a wait
        RawR qc, qw;
        load_raw(IM, o + 2, lane, c0, actL, actR, qc);
        load_raw(U,  o + 2, lane, c0, actL, actR, qw);
        R7 C, W;
        finish_row(qc, bpu, bpd, actL, actR, zL, zR, C);
        finish_row(qw, bpu, bpd, actL, actR, zL, zR, W);

        // e / px / py at row o+1 (img rows o,o+1,o+2 ; u rows o..o+2)
        float eN[6], PXN[6], PYN[5];
        const bool rowv = (o >= -1) && (o < HH - 1);   // wave-uniform row validity
        if (rowv) {
            #pragma unroll
            for (int k = 1; k <= 4; ++k) {
                float ex = (I0.v[k-1] - I0.v[k+1]) + 2.f * (I1.v[k-1] - I1.v[k+1]) + (C.v[k-1] - C.v[k+1]);
                float ey = (I0.v[k-1] - C.v[k-1]) + 2.f * (I0.v[k] - C.v[k]) + (I0.v[k+1] - C.v[k+1]);
                float s2 = ex * ex + ey * ey;
                eN[k] = M * __builtin_amdgcn_rcpf(s2 * s2 + M);
                float gux = R2.v[k+1] - R2.v[k-1];
                float guy = R1.v[k] - W.v[k];
                float rn  = __builtin_amdgcn_rsqf(gux * gux + guy * guy + EPSF);
                PXN[k] = gux * rn;
                PYN[k] = guy * rn;
            }
        } else {
            #pragma unroll
            for (int k = 1; k <= 4; ++k) { eN[k] = 0.f; PXN[k] = 0.f; PYN[k] = 0.f; }
        }
        {   // halos for eN / PXN: interior lanes via bperm, image borders zero
            float a = bperm(bpu, eN[4]),  bb = bperm(bpd, eN[1]);
            float c = bperm(bpu, PXN[4]), d  = bperm(bpd, PXN[1]);
            eN[0]  = zL ? 0.f : a;  eN[5]  = zR ? 0.f : bb;
            PXN[0] = zL ? 0.f : c;  PXN[5] = zR ? 0.f : d;
        }
        if (rowv && (actL | actR)) {
            // panel-boundary halo column: recompute e/px locally on the edge lane
            float i0a = actL ? I0.x    : I0.v[4];
            float i0b = actL ? I0.v[0] : I0.v[5];
            float i0c = actL ? I0.v[1] : I0.x;
            float i1a = actL ? I1.x    : I1.v[4];
            float i1c = actL ? I1.v[1] : I1.x;
            float ca  = actL ? C.x     : C.v[4];
            float cb  = actL ? C.v[0]  : C.v[5];
            float cc  = actL ? C.v[1]  : C.x;
            float ex = (i0a - i0c) + 2.f * (i1a - i1c) + (ca - cc);
            float ey = (i0a - ca) + 2.f * (i0b - cb) + (i0c - cc);
            float s2 = ex * ex + ey * ey;
            float eh = M * __builtin_amdgcn_rcpf(s2 * s2 + M);
            float gux = actL ? (R2.v[1] - R2.x)    : (R2.x - R2.v[4]);
            float guy = actL ? (R1.v[0] - W.v[0])  : (R1.v[5] - W.v[5]);
            float rn = __builtin_amdgcn_rsqf(gux * gux + guy * guy + EPSF);
            float ph = gux * rn;
            if (actL) { eN[0] = eh; PXN[0] = ph; }
            else      { eN[5] = eh; PXN[5] = ph; }
        }

        if (o >= o0) {   // emit output row o
            float vals[4];
            #pragma unroll
            for (int k = 1; k <= 4; ++k) {
                float gex = E2[k+1] - E2[k-1];
                float gey = E1[k] - eN[k];
                float xp = R1.v[k+1] - R1.v[k], xn = R1.v[k] - R1.v[k-1];
                float yp = R0[k] - R1.v[k],     yn = R1.v[k] - R2.v[k];
                float tr = fmaxf(gex, 0.f) * xp + fminf(gex, 0.f) * xn
                         + fmaxf(gey, 0.f) * yp + fminf(gey, 0.f) * yn;
                float gxc = R1.v[k+1] - R1.v[k-1], gyc = R0[k] - R2.v[k];
                float ncv = __builtin_amdgcn_sqrtf(gxc * gxc + gyc * gyc + EPSF);
                float kap = (PX2[k+1] - PX2[k-1]) + (PY1[k] - PYN[k]);
                vals[k-1] = R1.v[k] + E2[k] * ncv * (kap * dta + dtg) + tr * dtb;
            }
            *(float4*)(O + (size_t)o * WW + c0 + 4 * lane) =
                make_float4(vals[0], vals[1], vals[2], vals[3]);
        }

        // roll
        I0 = I1; I1 = C;
        #pragma unroll
        for (int k = 1; k <= 4; ++k) { R0[k] = R1.v[k]; E1[k] = E2[k]; PY1[k] = PY2[k]; PY2[k] = PYN[k]; }
        R1 = R2; R2 = W;
        #pragma unroll
        for (int k = 0; k < 6; ++k) { E2[k] = eN[k]; PX2[k] = PXN[k]; }
    }
}

extern "C" void kernel_launch(void* const* d_in, const int* in_sizes, int n_in,
                              void* d_out, int out_size, void* d_ws, size_t ws_size,
                              hipStream_t stream) {
    const float* u   = (const float*)d_in[0];
    const float* img = (const float*)d_in[1];
    const float* pa  = (const float*)d_in[2];
    const float* pb  = (const float*)d_in[3];
    const float* pg  = (const float*)d_in[4];
    float* out = (float*)d_out;
    float* partial = (float*)d_ws;        // 4096 floats, all written unconditionally

    // pass 1: 128 strips x 32 batch = 4096 waves = 1024 blocks (4 blocks/CU)
    max_e4_kernel<<<1024, 256, 0, stream>>>(img, partial);
    // pass 2: 2 panels x 64 strips x 32 batch = 4096 waves = 1024 blocks (3 blocks/CU resident)
    fused_ff<<<1024, 256, 0, stream>>>(u, img, pa, pb, pg, partial, out);
}